// Round 5
// baseline (64.146 us; speedup 1.0000x reference)
//
#include <hip/hip_runtime.h>

#define HALFB 0.5f
#define CAPB  0.1f
#define NB 4            // row-groups per wave, software-pipelined

__device__ __forceinline__ float clip05(float z) {
    return fminf(fmaxf(z, -HALFB), HALFB);   // v_med3_f32
}

// Reductions across the 4-lane group that owns one row.
__device__ __forceinline__ float red4f(float v) {
    v += __shfl_xor(v, 1); v += __shfl_xor(v, 2); return v;
}
__device__ __forceinline__ int red4i(int v) {
    v += __shfl_xor(v, 1); v += __shfl_xor(v, 2); return v;
}
__device__ __forceinline__ float min4f(float v) {
    v = fminf(v, __shfl_xor(v, 1)); v = fminf(v, __shfl_xor(v, 2)); return v;
}
__device__ __forceinline__ float max4f(float v) {
    v = fmaxf(v, __shfl_xor(v, 1)); v = fmaxf(v, __shfl_xor(v, 2)); return v;
}

// 4 lanes per row, 32 elems/lane in VGPRs. Each wave handles NB row-groups,
// double-buffered: group k+1's global loads are issued before group k's solve,
// so L2/L3/HBM latency hides under ~2000 cycles of Newton VALU work.
__global__ __launch_bounds__(256, 4) void proj_kernel(
    const float* __restrict__ x, float* __restrict__ out, int nrows)
{
    const int lane   = threadIdx.x & 63;
    const int q      = lane & 3;                              // quarter of row
    const int rsub   = lane >> 2;                             // row-in-group
    const int wid    = (blockIdx.x << 2) | (threadIdx.x >> 6);
    const int nwaves = gridDim.x << 2;

    const float4* __restrict__ px = (const float4*)x;
    float4*       __restrict__ po = (float4*)out;

    float4 buf[2][8];

    // prologue: load group 0
    {
        const int row = (wid << 4) | rsub;
        const float4* p = px + ((size_t)row << 5) + (q << 3);
        #pragma unroll
        for (int j = 0; j < 8; ++j) buf[0][j] = p[j];
    }

    #pragma unroll
    for (int k = 0; k < NB; ++k) {            // fully unrolled -> static buf idx
        const int cb = k & 1;

        // prefetch group k+1 into the other buffer (issued before the solve)
        if (k + 1 < NB) {
            const int row = ((wid + (k + 1) * nwaves) << 4) | rsub;
            const float4* p = px + ((size_t)row << 5) + (q << 3);
            #pragma unroll
            for (int j = 0; j < 8; ++j) buf[cb ^ 1][j] = p[j];
        }

        // ---- solve on buf[cb] (identical math to rounds 2-4) ----
        const float4 (&v)[8] = buf[cb];
        float s0 = 0.f, vmn = 3.0e38f, vmx = -3.0e38f;
        int nai = 0;
        #pragma unroll
        for (int j = 0; j < 8; ++j) {
            const float a[4] = { v[j].x, v[j].y, v[j].z, v[j].w };
            #pragma unroll
            for (int e = 0; e < 4; ++e) {
                s0  += clip05(a[e]);
                nai += (fabsf(a[e]) < HALFB);
                vmn  = fminf(vmn, a[e]);
                vmx  = fmaxf(vmx, a[e]);
            }
        }
        s0  = red4f(s0);
        nai = red4i(nai);
        vmn = min4f(vmn);
        vmx = max4f(vmx);

        const float t = fminf(fmaxf(s0, -CAPB), CAPB);
        float g   = s0;
        float na  = (float)nai;
        float lo  = vmn - (HALFB + CAPB);
        float hi  = vmx + (HALFB + CAPB);
        float lam = 0.f;

        for (int it = 0; it < 20; ++it) {
            if (fabsf(g - t) <= 1e-4f) break;     // final division heals residual
            if (g > t) lo = lam; else hi = lam;   // g decreasing in lam
            float ln;
            if (na > 0.f) {
                ln = lam + (g - t) * __builtin_amdgcn_rcpf(na);
                if (!(ln > lo && ln < hi)) ln = 0.5f * (lo + hi);
            } else {
                ln = 0.5f * (lo + hi);
            }
            if (ln == lam) break;
            lam = ln;

            float gp = 0.f; int np = 0;
            #pragma unroll
            for (int j = 0; j < 8; ++j) {
                const float a[4] = { v[j].x, v[j].y, v[j].z, v[j].w };
                #pragma unroll
                for (int e = 0; e < 4; ++e) {
                    const float z = a[e] - lam;
                    gp += clip05(z);
                    np += (fabsf(z) < HALFB);
                }
            }
            g  = red4f(gp);
            na = (float)red4i(np);
        }

        // exact closed form over the active set (== reference's last step)
        const float lam_f = (na > 0.f) ? lam + (g - t) / na : lam;

        // store group k
        {
            const int row = ((wid + k * nwaves) << 4) | rsub;
            if (row < nrows) {
                float4* p = po + ((size_t)row << 5) + (q << 3);
                #pragma unroll
                for (int j = 0; j < 8; ++j)
                    p[j] = make_float4(clip05(v[j].x - lam_f), clip05(v[j].y - lam_f),
                                       clip05(v[j].z - lam_f), clip05(v[j].w - lam_f));
            }
        }
    }
}

extern "C" void kernel_launch(void* const* d_in, const int* in_sizes, int n_in,
                              void* d_out, int out_size, void* d_ws, size_t ws_size,
                              hipStream_t stream) {
    const float* x = (const float*)d_in[0];
    float* out     = (float*)d_out;
    const int nrows = out_size / 128;                      // 262144
    // per block: 4 waves x 16 rows x NB groups = 256 rows
    const int grid  = (nrows + 64 * NB - 1) / (64 * NB);   // 1024
    hipLaunchKernelGGL(proj_kernel, dim3(grid), dim3(256), 0, stream, x, out, nrows);
}